// Round 9
// baseline (536.947 us; speedup 1.0000x reference)
//
#include <hip/hip_runtime.h>

typedef __attribute__((ext_vector_type(8))) short bf16x8;
typedef __attribute__((ext_vector_type(8))) unsigned short u16x8;
typedef __attribute__((ext_vector_type(4))) float f32x4;
typedef __attribute__((ext_vector_type(2))) unsigned uint2v;

#define DEVINL __device__ __forceinline__

constexpr int TB = 2;        // batch
constexpr int TT = 4096;     // seq len
constexpr int TD = 512;      // model dim
constexpr int TH = 8;        // heads
constexpr int THD = 64;      // head dim
constexpr int TM = TB * TT;  // 8192 flattened rows

// fp32 -> bf16 round-to-nearest-even
DEVINL unsigned short f2b(float f) {
  unsigned u = __builtin_bit_cast(unsigned, f);
  u += 0x7FFFu + ((u >> 16) & 1u);
  return (unsigned short)(u >> 16);
}

// pack 2 f32 -> 2 bf16 in one dword (lo -> low16, hi -> high16), RNE
DEVINL unsigned cvtpk(float lo, float hi) {
  unsigned r;
  asm("v_cvt_pk_bf16_f32 %0, %1, %2" : "=v"(r) : "v"(lo), "v"(hi));
  return r;
}

// barrier that only waits LDS ops (global stores may stay in flight)
DEVINL void lgkm_barrier() {
  asm volatile("s_waitcnt lgkmcnt(0)" ::: "memory");
  __builtin_amdgcn_s_barrier();
  __builtin_amdgcn_sched_barrier(0);
}

// ---------------------------------------------------------------------------
// Fused Q/K/V projection: one dispatch, blockIdx.z selects {X, W, out, mode}.
// z=0: queries@Wq^T -> qb row-major bf16
// z=1: keys   @Wk^T -> kb row-major bf16
// z=2: values @Wv^T -> vt per-head transposed VT[b][h][d][T] (swapped mfma)
// 128x128 tile, BK=64, 4 waves. 768 blocks -> whole device busy at once.
// ---------------------------------------------------------------------------
__global__ __launch_bounds__(256, 2)
void proj_qkv(const float* __restrict__ Xq, const float* __restrict__ Xk,
              const float* __restrict__ Xv, const float* __restrict__ Wq,
              const float* __restrict__ Wk, const float* __restrict__ Wv,
              unsigned short* __restrict__ qb, unsigned short* __restrict__ kb,
              unsigned short* __restrict__ vt)
{
  constexpr int K = TD, N = TD;
  __shared__ unsigned short As[128][72];
  __shared__ unsigned short Bs[128][72];

  const int z = blockIdx.z;
  const float* X = (z == 0) ? Xq : (z == 1) ? Xk : Xv;
  const float* W = (z == 0) ? Wq : (z == 1) ? Wk : Wv;
  unsigned short* Yb = (z == 0) ? qb : (z == 1) ? kb : vt;
  const bool TR = (z == 2);

  const int t    = threadIdx.x;
  const int lane = t & 63, w = t >> 6;
  const int fr = lane & 15, fq = lane >> 4;
  const int wr = (w >> 1) * 64, wc = (w & 1) * 64;
  const int bm = blockIdx.x * 128, bn = blockIdx.y * 128;
  const int srow = t >> 1;
  const int skh  = (t & 1) * 32;

  f32x4 acc[4][4];
  #pragma unroll
  for (int i = 0; i < 4; ++i)
    #pragma unroll
    for (int j = 0; j < 4; ++j)
      acc[i][j] = f32x4{0.f, 0.f, 0.f, 0.f};

  for (int k0 = 0; k0 < K; k0 += 64) {
    const float* srcA = X + (size_t)(bm + srow) * K + k0 + skh;
    const float* srcB = W + (size_t)(bn + srow) * K + k0 + skh;
    #pragma unroll
    for (int i = 0; i < 4; ++i) {
      float4 a0 = ((const float4*)srcA)[2 * i];
      float4 a1 = ((const float4*)srcA)[2 * i + 1];
      u16x8 oa = {f2b(a0.x), f2b(a0.y), f2b(a0.z), f2b(a0.w),
                  f2b(a1.x), f2b(a1.y), f2b(a1.z), f2b(a1.w)};
      *(u16x8*)&As[srow][skh + i * 8] = oa;
      float4 b0 = ((const float4*)srcB)[2 * i];
      float4 b1 = ((const float4*)srcB)[2 * i + 1];
      u16x8 ob = {f2b(b0.x), f2b(b0.y), f2b(b0.z), f2b(b0.w),
                  f2b(b1.x), f2b(b1.y), f2b(b1.z), f2b(b1.w)};
      *(u16x8*)&Bs[srow][skh + i * 8] = ob;
    }
    __syncthreads();
    #pragma unroll
    for (int kk = 0; kk < 2; ++kk) {
      bf16x8 af[4], bfv[4];
      #pragma unroll
      for (int i = 0; i < 4; ++i)
        af[i] = *(const bf16x8*)&As[wr + i * 16 + fr][kk * 32 + fq * 8];
      #pragma unroll
      for (int j = 0; j < 4; ++j)
        bfv[j] = *(const bf16x8*)&Bs[wc + j * 16 + fr][kk * 32 + fq * 8];
      if (TR) {
        #pragma unroll
        for (int i = 0; i < 4; ++i)
          #pragma unroll
          for (int j = 0; j < 4; ++j)
            acc[i][j] = __builtin_amdgcn_mfma_f32_16x16x32_bf16(bfv[i], af[j], acc[i][j], 0, 0, 0);
      } else {
        #pragma unroll
        for (int i = 0; i < 4; ++i)
          #pragma unroll
          for (int j = 0; j < 4; ++j)
            acc[i][j] = __builtin_amdgcn_mfma_f32_16x16x32_bf16(af[i], bfv[j], acc[i][j], 0, 0, 0);
      }
    }
    __syncthreads();
  }

  if (TR) {
    // D rows = N-dim (from Bs), D cols = M-dim (from As)
    #pragma unroll
    for (int i = 0; i < 4; ++i)
      #pragma unroll
      for (int j = 0; j < 4; ++j)
        #pragma unroll
        for (int ii = 0; ii < 4; ++ii) {
          const int Nidx = bn + wc + i * 16 + fq * 4 + ii;
          const int Midx = bm + wr + j * 16 + fr;
          const int h = Nidx >> 6, d = Nidx & (THD - 1);
          const int b = Midx >> 12, tt = Midx & (TT - 1);
          Yb[((size_t)(b * TH + h) * THD + d) * TT + tt] = f2b(acc[i][j][ii]);
        }
  } else {
    #pragma unroll
    for (int i = 0; i < 4; ++i)
      #pragma unroll
      for (int j = 0; j < 4; ++j)
        #pragma unroll
        for (int ii = 0; ii < 4; ++ii) {
          const int gm = bm + wr + i * 16 + fq * 4 + ii;
          const int gn = bn + wc + j * 16 + fr;
          Yb[(size_t)gm * N + gn] = f2b(acc[i][j][ii]);
        }
  }
}

// ---------------------------------------------------------------------------
// Final GEMM: out = zf @ Wo^T + bo (fp32 out).  Same 128x128 tile.
// ---------------------------------------------------------------------------
__global__ __launch_bounds__(256, 2)
void gemm_final(const float* __restrict__ X, const float* __restrict__ W,
                float* __restrict__ Yf, const float* __restrict__ bias)
{
  constexpr int K = TD, N = TD;
  __shared__ unsigned short As[128][72];
  __shared__ unsigned short Bs[128][72];

  const int t    = threadIdx.x;
  const int lane = t & 63, w = t >> 6;
  const int fr = lane & 15, fq = lane >> 4;
  const int wr = (w >> 1) * 64, wc = (w & 1) * 64;
  const int bm = blockIdx.x * 128, bn = blockIdx.y * 128;
  const int srow = t >> 1;
  const int skh  = (t & 1) * 32;

  f32x4 acc[4][4];
  #pragma unroll
  for (int i = 0; i < 4; ++i)
    #pragma unroll
    for (int j = 0; j < 4; ++j)
      acc[i][j] = f32x4{0.f, 0.f, 0.f, 0.f};

  for (int k0 = 0; k0 < K; k0 += 64) {
    const float* srcA = X + (size_t)(bm + srow) * K + k0 + skh;
    const float* srcB = W + (size_t)(bn + srow) * K + k0 + skh;
    #pragma unroll
    for (int i = 0; i < 4; ++i) {
      float4 a0 = ((const float4*)srcA)[2 * i];
      float4 a1 = ((const float4*)srcA)[2 * i + 1];
      u16x8 oa = {f2b(a0.x), f2b(a0.y), f2b(a0.z), f2b(a0.w),
                  f2b(a1.x), f2b(a1.y), f2b(a1.z), f2b(a1.w)};
      *(u16x8*)&As[srow][skh + i * 8] = oa;
      float4 b0 = ((const float4*)srcB)[2 * i];
      float4 b1 = ((const float4*)srcB)[2 * i + 1];
      u16x8 ob = {f2b(b0.x), f2b(b0.y), f2b(b0.z), f2b(b0.w),
                  f2b(b1.x), f2b(b1.y), f2b(b1.z), f2b(b1.w)};
      *(u16x8*)&Bs[srow][skh + i * 8] = ob;
    }
    __syncthreads();
    #pragma unroll
    for (int kk = 0; kk < 2; ++kk) {
      bf16x8 af[4], bfv[4];
      #pragma unroll
      for (int i = 0; i < 4; ++i)
        af[i] = *(const bf16x8*)&As[wr + i * 16 + fr][kk * 32 + fq * 8];
      #pragma unroll
      for (int j = 0; j < 4; ++j)
        bfv[j] = *(const bf16x8*)&Bs[wc + j * 16 + fr][kk * 32 + fq * 8];
      #pragma unroll
      for (int i = 0; i < 4; ++i)
        #pragma unroll
        for (int j = 0; j < 4; ++j)
          acc[i][j] = __builtin_amdgcn_mfma_f32_16x16x32_bf16(af[i], bfv[j], acc[i][j], 0, 0, 0);
    }
    __syncthreads();
  }

  #pragma unroll
  for (int i = 0; i < 4; ++i)
    #pragma unroll
    for (int j = 0; j < 4; ++j)
      #pragma unroll
      for (int ii = 0; ii < 4; ++ii) {
        const int gm = bm + wr + i * 16 + fq * 4 + ii;
        const int gn = bn + wc + j * 16 + fr;
        Yf[(size_t)gm * N + gn] = acc[i][j][ii] + bias[gn];
      }
}

// ---------------------------------------------------------------------------
// Fused attention (r8 structure, ONLY the store flavor changed):
// plain write-back stores instead of nontemporal -> L2 write-combining of the
// 64B row-fragments into full lines before DRAM.
// ---------------------------------------------------------------------------
__global__ __launch_bounds__(256, 4)
void attn_fused(const unsigned short* __restrict__ Qb,
                const unsigned short* __restrict__ Kb,
                const unsigned short* __restrict__ VTg,
                float* __restrict__ attnO, float* __restrict__ Z)
{
  __shared__ unsigned short Ks[2][32][72];     // 9.0 KB  K rows [kv][d]
  __shared__ unsigned short VTs[2][64][40];    // 10.0 KB V^T rows [d][kv]
  __shared__ unsigned short Ps[4][16][40];     // 5.0 KB  per-wave P [q][kv]

  const int t    = threadIdx.x;
  const int lane = t & 63, w = t >> 6;         // w = 0..3 (q sixteenth)
  const int fr = lane & 15, fq = lane >> 4;
  const int bh = blockIdx.y;                   // b*8+h
  const int b  = bh >> 3, h = bh & 7;
  const int q0 = blockIdx.x * 64;

  const size_t rowKV  = ((size_t)(b * TT)) * TD + h * THD;
  const size_t vtBase = (size_t)bh * THD * TT;

  const int trK = t >> 3, tcK = (t & 7) * 8;
  const int trV = t >> 2, tcV = (t & 3) * 8;

  auto loadK = [&](int kv0, u16x8& r) {
    r = *(const u16x8*)(Kb + rowKV + (size_t)(kv0 + trK) * TD + tcK);
  };
  auto loadVT = [&](int kv0, u16x8& r) {
    r = *(const u16x8*)(VTg + vtBase + (size_t)trV * TT + kv0 + tcV);
  };
  auto writeK  = [&](int buf, const u16x8& r) { *(u16x8*)&Ks[buf][trK][tcK]  = r; };
  auto writeVT = [&](int buf, const u16x8& r) { *(u16x8*)&VTs[buf][trV][tcV] = r; };

  // Q held in registers (B-operand of swapped QK; row = q = w*16+fr)
  const unsigned short* qsrc = Qb + ((size_t)(b * TT + q0 + w * 16 + fr)) * TD + h * THD;
  bf16x8 aq[2];
  aq[0] = *(const bf16x8*)(qsrc + fq * 8);
  aq[1] = *(const bf16x8*)(qsrc + 32 + fq * 8);

  constexpr int KVB = 32;
  constexpr int NT = TT / KVB;                 // 128 kv tiles
  constexpr float K2 = 0.18033688011112042f;   // (1/8) * log2(e)

  u16x8 kr, vr;
  loadK(0, kr);
  writeK(0, kr);
  lgkm_barrier();

  // ---- pass 1: row sums of exp(s/8) ----
  float lsum = 0.f;
  for (int j = 0; j < NT; ++j) {
    const int cur = j & 1;
    if (j + 1 < NT) loadK((j + 1) * KVB, kr);
    __builtin_amdgcn_s_setprio(1);
    #pragma unroll
    for (int n = 0; n < 2; ++n) {
      f32x4 s = f32x4{0.f, 0.f, 0.f, 0.f};
      #pragma unroll
      for (int kk = 0; kk < 2; ++kk) {
        bf16x8 ak = *(const bf16x8*)&Ks[cur][n * 16 + fr][kk * 32 + fq * 8];
        s = __builtin_amdgcn_mfma_f32_16x16x32_bf16(ak, aq[kk], s, 0, 0, 0);
      }
      #pragma unroll
      for (int i = 0; i < 4; ++i)
        lsum += __builtin_amdgcn_exp2f(s[i] * K2);
    }
    __builtin_amdgcn_s_setprio(0);
    if (j + 1 < NT) writeK(cur ^ 1, kr);
    lgkm_barrier();
  }
  lsum += __shfl_xor(lsum, 16, 64);
  lsum += __shfl_xor(lsum, 32, 64);
  const float l2i = -__log2f(lsum);    // log2(1/lsum)

  // ---- pass 2: recompute, write attn (plain stores), accumulate PV ----
  loadK(0, kr);
  loadVT(0, vr);
  writeK(0, kr);
  writeVT(0, vr);
  lgkm_barrier();

  f32x4 accz[4];
  #pragma unroll
  for (int n = 0; n < 4; ++n) accz[n] = f32x4{0.f, 0.f, 0.f, 0.f};

  float* arow = attnO + ((size_t)bh * TT + q0 + w * 16 + fr) * TT + fq * 4;

  for (int j = 0; j < NT; ++j) {
    const int cur = j & 1;
    const int kv0 = j * KVB;
    if (j + 1 < NT) {
      loadK((j + 1) * KVB, kr);
      loadVT((j + 1) * KVB, vr);
    }
    f32x4 sv[2];
    __builtin_amdgcn_s_setprio(1);
    #pragma unroll
    for (int n = 0; n < 2; ++n) {
      f32x4 s = f32x4{0.f, 0.f, 0.f, 0.f};
      #pragma unroll
      for (int kk = 0; kk < 2; ++kk) {
        bf16x8 ak = *(const bf16x8*)&Ks[cur][n * 16 + fr][kk * 32 + fq * 8];
        s = __builtin_amdgcn_mfma_f32_16x16x32_bf16(ak, aq[kk], s, 0, 0, 0);
      }
      sv[n] = s;
    }
    __builtin_amdgcn_s_setprio(0);
    #pragma unroll
    for (int n = 0; n < 2; ++n) {
      float p0 = __builtin_amdgcn_exp2f(fmaf(sv[n][0], K2, l2i));
      float p1 = __builtin_amdgcn_exp2f(fmaf(sv[n][1], K2, l2i));
      float p2 = __builtin_amdgcn_exp2f(fmaf(sv[n][2], K2, l2i));
      float p3 = __builtin_amdgcn_exp2f(fmaf(sv[n][3], K2, l2i));
      f32x4 pv4 = {p0, p1, p2, p3};
      *(f32x4*)(arow + kv0 + n * 16) = pv4;          // plain write-back store
      uint2v u = {cvtpk(p0, p1), cvtpk(p2, p3)};
      *(uint2v*)&Ps[w][fr][n * 16 + fq * 4] = u;
    }
    asm volatile("s_waitcnt lgkmcnt(0)" ::: "memory");
    __builtin_amdgcn_sched_barrier(0);
    __builtin_amdgcn_s_setprio(1);
    {
      bf16x8 ap = *(const bf16x8*)&Ps[w][fr][fq * 8];
      #pragma unroll
      for (int df = 0; df < 4; ++df) {
        bf16x8 bv = *(const bf16x8*)&VTs[cur][df * 16 + fr][fq * 8];
        accz[df] = __builtin_amdgcn_mfma_f32_16x16x32_bf16(ap, bv, accz[df], 0, 0, 0);
      }
    }
    __builtin_amdgcn_s_setprio(0);
    if (j + 1 < NT) {
      writeK(cur ^ 1, kr);
      writeVT(cur ^ 1, vr);
    }
    lgkm_barrier();
  }

  // Z in [B*T, D]; accz[df][i] = Z[q = q0+w*16+fq*4+i][d = df*16+fr]
  const size_t zbase = ((size_t)(b * TT + q0 + w * 16 + fq * 4)) * TD + h * THD + fr;
  #pragma unroll
  for (int df = 0; df < 4; ++df)
    #pragma unroll
    for (int i = 0; i < 4; ++i)
      Z[zbase + (size_t)i * TD + df * 16] = accz[df][i];
}

// ---------------------------------------------------------------------------
extern "C" void kernel_launch(void* const* d_in, const int* in_sizes, int n_in,
                              void* d_out, int out_size, void* d_ws, size_t ws_size,
                              hipStream_t stream) {
  const float* queries = (const float*)d_in[0];
  const float* keys    = (const float*)d_in[1];
  const float* values  = (const float*)d_in[2];
  const float* Wq = (const float*)d_in[3];
  const float* Wk = (const float*)d_in[4];
  const float* Wv = (const float*)d_in[5];
  const float* Wo = (const float*)d_in[6];
  const float* bo = (const float*)d_in[7];

  float* out  = (float*)d_out;                       // [2,4096,512]
  float* attn = out + (size_t)TM * TD;               // [2,8,4096,4096]

  unsigned short* qb = (unsigned short*)d_ws;
  unsigned short* kb = qb + (size_t)TM * TD;
  unsigned short* vt = kb + (size_t)TM * TD;
  float*          zf = (float*)(vt + (size_t)TM * TD);

  proj_qkv<<<dim3(TM / 128, TD / 128, 3), 256, 0, stream>>>(
      queries, keys, values, Wq, Wk, Wv, qb, kb, vt);

  attn_fused<<<dim3(TT / 64, TB * TH), 256, 0, stream>>>(qb, kb, vt, attn, zf);

  gemm_final<<<dim3(TM / 128, TD / 128), 256, 0, stream>>>(zf, Wo, out, bo);
}

// Round 10
// 521.797 us; speedup vs baseline: 1.0290x; 1.0290x over previous
//
#include <hip/hip_runtime.h>

typedef __attribute__((ext_vector_type(8))) short bf16x8;
typedef __attribute__((ext_vector_type(8))) unsigned short u16x8;
typedef __attribute__((ext_vector_type(4))) float f32x4;
typedef __attribute__((ext_vector_type(2))) unsigned uint2v;
typedef __attribute__((ext_vector_type(4))) unsigned uint4v;

#define DEVINL __device__ __forceinline__

constexpr int TB = 2;        // batch
constexpr int TT = 4096;     // seq len
constexpr int TD = 512;      // model dim
constexpr int TH = 8;        // heads
constexpr int THD = 64;      // head dim
constexpr int TM = TB * TT;  // 8192 flattened rows

// fp32 -> bf16 round-to-nearest-even
DEVINL unsigned short f2b(float f) {
  unsigned u = __builtin_bit_cast(unsigned, f);
  u += 0x7FFFu + ((u >> 16) & 1u);
  return (unsigned short)(u >> 16);
}

// pack 2 f32 -> 2 bf16 in one dword (lo -> low16, hi -> high16), RNE
DEVINL unsigned cvtpk(float lo, float hi) {
  unsigned r;
  asm("v_cvt_pk_bf16_f32 %0, %1, %2" : "=v"(r) : "v"(lo), "v"(hi));
  return r;
}

// barrier that only waits LDS ops (global stores may stay in flight)
DEVINL void lgkm_barrier() {
  asm volatile("s_waitcnt lgkmcnt(0)" ::: "memory");
  __builtin_amdgcn_s_barrier();
  __builtin_amdgcn_sched_barrier(0);
}

// ---------------------------------------------------------------------------
// Fused Q/K/V projection: one dispatch, blockIdx.z selects {X, W, out, mode}.
// z=0: queries@Wq^T -> qb row-major; z=1: keys@Wk^T -> kb row-major;
// z=2: values@Wv^T -> vt per-head transposed VT[b][h][d][T] (swapped mfma).
// ---------------------------------------------------------------------------
__global__ __launch_bounds__(256, 2)
void proj_qkv(const float* __restrict__ Xq, const float* __restrict__ Xk,
              const float* __restrict__ Xv, const float* __restrict__ Wq,
              const float* __restrict__ Wk, const float* __restrict__ Wv,
              unsigned short* __restrict__ qb, unsigned short* __restrict__ kb,
              unsigned short* __restrict__ vt)
{
  constexpr int K = TD, N = TD;
  __shared__ unsigned short As[128][72];
  __shared__ unsigned short Bs[128][72];

  const int z = blockIdx.z;
  const float* X = (z == 0) ? Xq : (z == 1) ? Xk : Xv;
  const float* W = (z == 0) ? Wq : (z == 1) ? Wk : Wv;
  unsigned short* Yb = (z == 0) ? qb : (z == 1) ? kb : vt;
  const bool TR = (z == 2);

  const int t    = threadIdx.x;
  const int lane = t & 63, w = t >> 6;
  const int fr = lane & 15, fq = lane >> 4;
  const int wr = (w >> 1) * 64, wc = (w & 1) * 64;
  const int bm = blockIdx.x * 128, bn = blockIdx.y * 128;
  const int srow = t >> 1;
  const int skh  = (t & 1) * 32;

  f32x4 acc[4][4];
  #pragma unroll
  for (int i = 0; i < 4; ++i)
    #pragma unroll
    for (int j = 0; j < 4; ++j)
      acc[i][j] = f32x4{0.f, 0.f, 0.f, 0.f};

  for (int k0 = 0; k0 < K; k0 += 64) {
    const float* srcA = X + (size_t)(bm + srow) * K + k0 + skh;
    const float* srcB = W + (size_t)(bn + srow) * K + k0 + skh;
    #pragma unroll
    for (int i = 0; i < 4; ++i) {
      float4 a0 = ((const float4*)srcA)[2 * i];
      float4 a1 = ((const float4*)srcA)[2 * i + 1];
      u16x8 oa = {f2b(a0.x), f2b(a0.y), f2b(a0.z), f2b(a0.w),
                  f2b(a1.x), f2b(a1.y), f2b(a1.z), f2b(a1.w)};
      *(u16x8*)&As[srow][skh + i * 8] = oa;
      float4 b0 = ((const float4*)srcB)[2 * i];
      float4 b1 = ((const float4*)srcB)[2 * i + 1];
      u16x8 ob = {f2b(b0.x), f2b(b0.y), f2b(b0.z), f2b(b0.w),
                  f2b(b1.x), f2b(b1.y), f2b(b1.z), f2b(b1.w)};
      *(u16x8*)&Bs[srow][skh + i * 8] = ob;
    }
    __syncthreads();
    #pragma unroll
    for (int kk = 0; kk < 2; ++kk) {
      bf16x8 af[4], bfv[4];
      #pragma unroll
      for (int i = 0; i < 4; ++i)
        af[i] = *(const bf16x8*)&As[wr + i * 16 + fr][kk * 32 + fq * 8];
      #pragma unroll
      for (int j = 0; j < 4; ++j)
        bfv[j] = *(const bf16x8*)&Bs[wc + j * 16 + fr][kk * 32 + fq * 8];
      if (TR) {
        #pragma unroll
        for (int i = 0; i < 4; ++i)
          #pragma unroll
          for (int j = 0; j < 4; ++j)
            acc[i][j] = __builtin_amdgcn_mfma_f32_16x16x32_bf16(bfv[i], af[j], acc[i][j], 0, 0, 0);
      } else {
        #pragma unroll
        for (int i = 0; i < 4; ++i)
          #pragma unroll
          for (int j = 0; j < 4; ++j)
            acc[i][j] = __builtin_amdgcn_mfma_f32_16x16x32_bf16(af[i], bfv[j], acc[i][j], 0, 0, 0);
      }
    }
    __syncthreads();
  }

  if (TR) {
    #pragma unroll
    for (int i = 0; i < 4; ++i)
      #pragma unroll
      for (int j = 0; j < 4; ++j)
        #pragma unroll
        for (int ii = 0; ii < 4; ++ii) {
          const int Nidx = bn + wc + i * 16 + fq * 4 + ii;
          const int Midx = bm + wr + j * 16 + fr;
          const int h = Nidx >> 6, dd = Nidx & (THD - 1);
          const int b = Midx >> 12, tt = Midx & (TT - 1);
          Yb[((size_t)(b * TH + h) * THD + dd) * TT + tt] = f2b(acc[i][j][ii]);
        }
  } else {
    #pragma unroll
    for (int i = 0; i < 4; ++i)
      #pragma unroll
      for (int j = 0; j < 4; ++j)
        #pragma unroll
        for (int ii = 0; ii < 4; ++ii) {
          const int gm = bm + wr + i * 16 + fq * 4 + ii;
          const int gn = bn + wc + j * 16 + fr;
          Yb[(size_t)gm * N + gn] = f2b(acc[i][j][ii]);
        }
  }
}

// ---------------------------------------------------------------------------
// Final GEMM: out = zf @ Wo^T + bo (fp32 out).
// ---------------------------------------------------------------------------
__global__ __launch_bounds__(256, 2)
void gemm_final(const float* __restrict__ X, const float* __restrict__ W,
                float* __restrict__ Yf, const float* __restrict__ bias)
{
  constexpr int K = TD, N = TD;
  __shared__ unsigned short As[128][72];
  __shared__ unsigned short Bs[128][72];

  const int t    = threadIdx.x;
  const int lane = t & 63, w = t >> 6;
  const int fr = lane & 15, fq = lane >> 4;
  const int wr = (w >> 1) * 64, wc = (w & 1) * 64;
  const int bm = blockIdx.x * 128, bn = blockIdx.y * 128;
  const int srow = t >> 1;
  const int skh  = (t & 1) * 32;

  f32x4 acc[4][4];
  #pragma unroll
  for (int i = 0; i < 4; ++i)
    #pragma unroll
    for (int j = 0; j < 4; ++j)
      acc[i][j] = f32x4{0.f, 0.f, 0.f, 0.f};

  for (int k0 = 0; k0 < K; k0 += 64) {
    const float* srcA = X + (size_t)(bm + srow) * K + k0 + skh;
    const float* srcB = W + (size_t)(bn + srow) * K + k0 + skh;
    #pragma unroll
    for (int i = 0; i < 4; ++i) {
      float4 a0 = ((const float4*)srcA)[2 * i];
      float4 a1 = ((const float4*)srcA)[2 * i + 1];
      u16x8 oa = {f2b(a0.x), f2b(a0.y), f2b(a0.z), f2b(a0.w),
                  f2b(a1.x), f2b(a1.y), f2b(a1.z), f2b(a1.w)};
      *(u16x8*)&As[srow][skh + i * 8] = oa;
      float4 b0 = ((const float4*)srcB)[2 * i];
      float4 b1 = ((const float4*)srcB)[2 * i + 1];
      u16x8 ob = {f2b(b0.x), f2b(b0.y), f2b(b0.z), f2b(b0.w),
                  f2b(b1.x), f2b(b1.y), f2b(b1.z), f2b(b1.w)};
      *(u16x8*)&Bs[srow][skh + i * 8] = ob;
    }
    __syncthreads();
    #pragma unroll
    for (int kk = 0; kk < 2; ++kk) {
      bf16x8 af[4], bfv[4];
      #pragma unroll
      for (int i = 0; i < 4; ++i)
        af[i] = *(const bf16x8*)&As[wr + i * 16 + fr][kk * 32 + fq * 8];
      #pragma unroll
      for (int j = 0; j < 4; ++j)
        bfv[j] = *(const bf16x8*)&Bs[wc + j * 16 + fr][kk * 32 + fq * 8];
      #pragma unroll
      for (int i = 0; i < 4; ++i)
        #pragma unroll
        for (int j = 0; j < 4; ++j)
          acc[i][j] = __builtin_amdgcn_mfma_f32_16x16x32_bf16(af[i], bfv[j], acc[i][j], 0, 0, 0);
    }
    __syncthreads();
  }

  #pragma unroll
  for (int i = 0; i < 4; ++i)
    #pragma unroll
    for (int j = 0; j < 4; ++j)
      #pragma unroll
      for (int ii = 0; ii < 4; ++ii) {
        const int gm = bm + wr + i * 16 + fq * 4 + ii;
        const int gn = bn + wc + j * 16 + fr;
        Yf[(size_t)gm * N + gn] = acc[i][j][ii] + bias[gn];
      }
}

// ---------------------------------------------------------------------------
// Fused attention, re-balanced two-pass:
//  pass 1 (no stores): QK -> p_unnorm = exp2(s*K2); lsum += p; PV with
//    UNNORMALIZED bf16 P held in registers (custom k-order shared with V's
//    two b64 reads -> no Ps LDS round-trip, no lgkm hard waits).
//    Z = accz / lsum via 4 shfl + rcp at the end (before pass 2).
//  pass 2 (store streamer): QK -> p = exp2(s*K2 + l2i) -> f32x4 store.
//    Nothing between stores but 4 MFMA + 8 exp; K-only staging.
// XCD swizzle: dispatch d -> bh = 2*(d&7) + ((d>>3)&1), q0 = (d>>4)*64
// (round-robin XCD assignment => each XCD sees 2 bh => K/V fit its 4MB L2).
// LDS ~19.7 KB; launch_bounds(256,4) => 4 blocks/CU, 16 waves/CU.
// ---------------------------------------------------------------------------
__global__ __launch_bounds__(256, 4)
void attn_fused(const unsigned short* __restrict__ Qb,
                const unsigned short* __restrict__ Kb,
                const unsigned short* __restrict__ VTg,
                float* __restrict__ attnO, float* __restrict__ Z)
{
  __shared__ unsigned short Ks[2][32][72];     // 9.0 KB  K rows [kv][d]
  __shared__ unsigned short VTs[2][64][40];    // 10.0 KB V^T rows [d][kv]

  const int t    = threadIdx.x;
  const int lane = t & 63, w = t >> 6;         // w = 0..3 (q sixteenth)
  const int fr = lane & 15, fq = lane >> 4;

  const int d  = blockIdx.x;                   // 0..1023
  const int bh = 2 * (d & 7) + ((d >> 3) & 1); // 2 bh per XCD
  const int q0 = (d >> 4) * 64;
  const int b  = bh >> 3, h = bh & 7;

  const size_t rowKV  = ((size_t)(b * TT)) * TD + h * THD;
  const size_t vtBase = (size_t)bh * THD * TT;

  const int trK = t >> 3, tcK = (t & 7) * 8;   // K staging 32x64
  const int trV = t >> 2, tcV = (t & 3) * 8;   // VT staging 64x32

  auto loadK = [&](int kv0, u16x8& r) {
    r = *(const u16x8*)(Kb + rowKV + (size_t)(kv0 + trK) * TD + tcK);
  };
  auto loadVT = [&](int kv0, u16x8& r) {
    r = *(const u16x8*)(VTg + vtBase + (size_t)trV * TT + kv0 + tcV);
  };
  auto writeK  = [&](int buf, const u16x8& r) { *(u16x8*)&Ks[buf][trK][tcK]  = r; };
  auto writeVT = [&](int buf, const u16x8& r) { *(u16x8*)&VTs[buf][trV][tcV] = r; };

  // Q held in registers (B-operand of swapped QK; row = q = w*16+fr)
  const unsigned short* qsrc = Qb + ((size_t)(b * TT + q0 + w * 16 + fr)) * TD + h * THD;
  bf16x8 aq[2];
  aq[0] = *(const bf16x8*)(qsrc + fq * 8);
  aq[1] = *(const bf16x8*)(qsrc + 32 + fq * 8);

  constexpr int KVB = 32;
  constexpr int NT = TT / KVB;                 // 128 kv tiles
  constexpr float K2 = 0.18033688011112042f;   // (1/8) * log2(e)

  u16x8 kr, vr;
  loadK(0, kr);
  loadVT(0, vr);
  writeK(0, kr);
  writeVT(0, vr);
  lgkm_barrier();

  // ---- pass 1: lsum + unnormalized PV (no global stores) ----
  float lsum = 0.f;
  f32x4 accz[4];
  #pragma unroll
  for (int n = 0; n < 4; ++n) accz[n] = f32x4{0.f, 0.f, 0.f, 0.f};

  for (int j = 0; j < NT; ++j) {
    const int cur = j & 1;
    if (j + 1 < NT) {
      loadK((j + 1) * KVB, kr);
      loadVT((j + 1) * KVB, vr);
    }
    f32x4 sv[2];
    __builtin_amdgcn_s_setprio(1);
    #pragma unroll
    for (int n = 0; n < 2; ++n) {
      f32x4 s = f32x4{0.f, 0.f, 0.f, 0.f};
      #pragma unroll
      for (int kk = 0; kk < 2; ++kk) {
        bf16x8 ak = *(const bf16x8*)&Ks[cur][n * 16 + fr][kk * 32 + fq * 8];
        s = __builtin_amdgcn_mfma_f32_16x16x32_bf16(ak, aq[kk], s, 0, 0, 0);
      }
      sv[n] = s;
    }
    __builtin_amdgcn_s_setprio(0);
    // p_unnorm = exp2(s*K2); lsum; pack P into A-frag (custom k-order:
    // k = fq*8+e -> kv = (e>>2)*16 + fq*4 + (e&3))
    float p[2][4];
    #pragma unroll
    for (int n = 0; n < 2; ++n)
      #pragma unroll
      for (int i = 0; i < 4; ++i) {
        p[n][i] = __builtin_amdgcn_exp2f(sv[n][i] * K2);
        lsum += p[n][i];
      }
    uint4v pav = {cvtpk(p[0][0], p[0][1]), cvtpk(p[0][2], p[0][3]),
                  cvtpk(p[1][0], p[1][1]), cvtpk(p[1][2], p[1][3])};
    bf16x8 ap = __builtin_bit_cast(bf16x8, pav);
    // PV: V with the same k-order via two b64 reads per df
    __builtin_amdgcn_s_setprio(1);
    #pragma unroll
    for (int df = 0; df < 4; ++df) {
      uint2v lo = *(const uint2v*)&VTs[cur][df * 16 + fr][fq * 4];
      uint2v hi = *(const uint2v*)&VTs[cur][df * 16 + fr][16 + fq * 4];
      uint4v bvv = {lo[0], lo[1], hi[0], hi[1]};
      accz[df] = __builtin_amdgcn_mfma_f32_16x16x32_bf16(
          ap, __builtin_bit_cast(bf16x8, bvv), accz[df], 0, 0, 0);
    }
    __builtin_amdgcn_s_setprio(0);
    if (j + 1 < NT) {
      writeK(cur ^ 1, kr);
      writeVT(cur ^ 1, vr);
    }
    lgkm_barrier();
  }

  // full row sums (q = w*16+fr is lane-local; kv split across fq)
  lsum += __shfl_xor(lsum, 16, 64);
  lsum += __shfl_xor(lsum, 32, 64);

  // ---- Z = accz / lsum; accz row i is q = w*16 + fq*4 + i ----
  float rls[4];
  #pragma unroll
  for (int i = 0; i < 4; ++i)
    rls[i] = 1.0f / __shfl(lsum, fq * 4 + i, 64);
  const size_t zbase = ((size_t)(b * TT + q0 + w * 16 + fq * 4)) * TD + h * THD + fr;
  #pragma unroll
  for (int df = 0; df < 4; ++df)
    #pragma unroll
    for (int i = 0; i < 4; ++i)
      Z[zbase + (size_t)i * TD + df * 16] = accz[df][i] * rls[i];

  // ---- pass 2: pure store streamer ----
  const float l2i = -__log2f(lsum);    // log2(1/lsum), lane-local q
  loadK(0, kr);
  writeK(0, kr);                        // Ks[0] free: last pass-1 tile used Ks[1]
  lgkm_barrier();

  float* arow = attnO + ((size_t)bh * TT + q0 + w * 16 + fr) * TT + fq * 4;

  for (int j = 0; j < NT; ++j) {
    const int cur = j & 1;
    if (j + 1 < NT) loadK((j + 1) * KVB, kr);
    f32x4 sv[2];
    __builtin_amdgcn_s_setprio(1);
    #pragma unroll
    for (int n = 0; n < 2; ++n) {
      f32x4 s = f32x4{0.f, 0.f, 0.f, 0.f};
      #pragma unroll
      for (int kk = 0; kk < 2; ++kk) {
        bf16x8 ak = *(const bf16x8*)&Ks[cur][n * 16 + fr][kk * 32 + fq * 8];
        s = __builtin_amdgcn_mfma_f32_16x16x32_bf16(ak, aq[kk], s, 0, 0, 0);
      }
      sv[n] = s;
    }
    __builtin_amdgcn_s_setprio(0);
    #pragma unroll
    for (int n = 0; n < 2; ++n) {
      f32x4 pv4 = {__builtin_amdgcn_exp2f(fmaf(sv[n][0], K2, l2i)),
                   __builtin_amdgcn_exp2f(fmaf(sv[n][1], K2, l2i)),
                   __builtin_amdgcn_exp2f(fmaf(sv[n][2], K2, l2i)),
                   __builtin_amdgcn_exp2f(fmaf(sv[n][3], K2, l2i))};
      *(f32x4*)(arow + j * KVB + n * 16) = pv4;
    }
    if (j + 1 < NT) writeK(cur ^ 1, kr);
    lgkm_barrier();
  }
}

// ---------------------------------------------------------------------------
extern "C" void kernel_launch(void* const* d_in, const int* in_sizes, int n_in,
                              void* d_out, int out_size, void* d_ws, size_t ws_size,
                              hipStream_t stream) {
  const float* queries = (const float*)d_in[0];
  const float* keys    = (const float*)d_in[1];
  const float* values  = (const float*)d_in[2];
  const float* Wq = (const float*)d_in[3];
  const float* Wk = (const float*)d_in[4];
  const float* Wv = (const float*)d_in[5];
  const float* Wo = (const float*)d_in[6];
  const float* bo = (const float*)d_in[7];

  float* out  = (float*)d_out;                       // [2,4096,512]
  float* attn = out + (size_t)TM * TD;               // [2,8,4096,4096]

  unsigned short* qb = (unsigned short*)d_ws;
  unsigned short* kb = qb + (size_t)TM * TD;
  unsigned short* vt = kb + (size_t)TM * TD;
  float*          zf = (float*)(vt + (size_t)TM * TD);

  proj_qkv<<<dim3(TM / 128, TD / 128, 3), 256, 0, stream>>>(
      queries, keys, values, Wq, Wk, Wv, qb, kb, vt);

  attn_fused<<<dim3(1024), 256, 0, stream>>>(qb, kb, vt, attn, zf);

  gemm_final<<<dim3(TM / 128, TD / 128), 256, 0, stream>>>(zf, Wo, out, bo);
}